// Round 9
// baseline (36.750 us; speedup 1.0000x reference)
//
#include <hip/hip_runtime.h>

#define OUT_N 5
#define TOTAL_NODES 65024
#define ROOTS_OFF (TOTAL_NODES * OUT_N)

typedef __attribute__((ext_vector_type(8))) short bf16x8;
typedef __attribute__((ext_vector_type(4))) float f32x4;
typedef __attribute__((ext_vector_type(8))) unsigned short ushort8v;
typedef __attribute__((ext_vector_type(4))) unsigned int uint4v;

static __device__ __forceinline__ unsigned short f2bf(float f) {
    union { float f; unsigned int i; } v; v.f = f;
    unsigned int r = v.i + 0x7fff + ((v.i >> 16) & 1);   // RNE
    return (unsigned short)(r >> 16);
}

// fp32 node row R (128 B), chunk c (0..7, 4 floats): chunk ROTATED by R.
// Rotation breaks the 128B-stride bank alignment AND implements the
// hi-rotation used by load_crot32 with compile-time indexing.
static __device__ __forceinline__ int naddr32(int R, int c) {
    return R * 128 + (((c + R) & 7) << 4);
}
static __device__ __forceinline__ void store_h32(char* smem, int R, int col, float v) {
    *(float*)(smem + naddr32(R, col >> 2) + (col & 3) * 4) = v;
}

// ---------------------------------------------------------------------------
// bprep: symmetric-pair B table (K=2144 -> 67 ksteps), MFMA-fragment order,
// bf16 (weights; rel-0.4% rounding only).
// ---------------------------------------------------------------------------
__global__ __launch_bounds__(64) void bprep_kernel(
    const float* __restrict__ V, const float* __restrict__ W,
    unsigned short* __restrict__ B)
{
    int t = blockIdx.x * 64 + threadIdx.x;
    if (t >= 8576) return;                   // 67*2*64
    int ks = t >> 7, sub = t & 127;
    int n = sub >> 6, lane = sub & 63;
    int hi = lane >> 4, l15 = lane & 15;
    int k = n * 16 + l15;
    const float* Vk = V + (size_t)k * 4096;
    ushort8v o;
    #pragma unroll
    for (int i = 0; i < 8; ++i) {
        int r5 = hi * 8 + i;
        float val;
        if (ks < 2)        { int j = 32 * ks + r5; val = Vk[j * 64 + j]; }
        else if (ks < 64)  { int d = ks >> 1; int j = 32 * (ks & 1) + r5; int l = (j + d) & 63;
                             val = Vk[j * 64 + l] + Vk[l * 64 + j]; }
        else if (ks == 64) { int j = r5; val = Vk[j * 64 + j + 32] + Vk[(j + 32) * 64 + j]; }
        else               { int j = (ks == 65) ? r5 : (32 + r5); val = W[j * 32 + k]; }
        o[i] = f2bf(val);
    }
    *(ushort8v*)(B + (size_t)t * 8) = o;
}

// ---------------------------------------------------------------------------
// crot[x] = c[(x + hi*8) & 63], fp32, from rotated-chunk LDS rows Rc, Rc+1.
// ---------------------------------------------------------------------------
static __device__ __forceinline__ void load_crot32(
    const char* nodes, int Rc, int hi, float* crot)
{
    #pragma unroll
    for (int t = 0; t < 16; ++t) {
        int m = (hi * 2 + t) & 15;           // chunk in 64-float c-space
        int row = Rc + (m >> 3), c4 = m & 7;
        f32x4 v = *(const f32x4*)(nodes + naddr32(row, c4));
        #pragma unroll
        for (int e = 0; e < 4; ++e) crot[t * 4 + e] = v[e];
    }
}

// ---------------------------------------------------------------------------
// Compile-time k-range, BOTH ntiles per wave (one A-build -> 2 MFMAs).
// A products computed in fp32, single-rounded to bf16 via cvt_pk.
// ---------------------------------------------------------------------------
template<int K0, int K1>
static __device__ __forceinline__ void run2_k(
    const unsigned short* __restrict__ Bg, const float* crot,
    int lane, f32x4& a0, f32x4& a1)
{
    const char* bp = (const char*)Bg + lane * 16;
    #pragma unroll
    for (int ks = K0; ks < K1; ++ks) {
        uint4v aw;
        #pragma unroll
        for (int q = 0; q < 4; ++q) {
            int i0 = 2 * q, i1 = 2 * q + 1;
            float p0, p1;
            if (ks < 2)       { p0 = crot[32*ks+i0] * crot[32*ks+i0];
                                p1 = crot[32*ks+i1] * crot[32*ks+i1]; }
            else if (ks < 64) { const int bse = 32 * (ks & 1), d = ks >> 1;
                                p0 = crot[bse+i0] * crot[(bse+i0+d)&63];
                                p1 = crot[bse+i1] * crot[(bse+i1+d)&63]; }
            else if (ks == 64){ p0 = crot[i0] * crot[32+i0];
                                p1 = crot[i1] * crot[32+i1]; }
            else if (ks == 65){ p0 = crot[i0];    p1 = crot[i1]; }
            else              { p0 = crot[32+i0]; p1 = crot[32+i1]; }
            unsigned int pk;
            asm("v_cvt_pk_bf16_f32 %0, %1, %2" : "=v"(pk) : "v"(p0), "v"(p1));
            aw[q] = pk;
        }
        bf16x8 afr = __builtin_bit_cast(bf16x8, aw);
        bf16x8 b0 = *(const bf16x8*)(bp + (ks << 11));
        bf16x8 b1 = *(const bf16x8*)(bp + (ks << 11) + 1024);
        a0 = __builtin_amdgcn_mfma_f32_16x16x32_bf16(afr, b0, a0, 0, 0, 0);
        a1 = __builtin_amdgcn_mfma_f32_16x16x32_bf16(afr, b1, a1, 0, 0, 0);
    }
}

// log_softmax from 32 fp32 h values in rotated LDS row R -> out[g*5..]
static __device__ __forceinline__ void node_logits32(
    const char* smem, int R, const float* __restrict__ Wout_w,
    const float* __restrict__ Wout_b, float* __restrict__ out, size_t g)
{
    float h[32];
    #pragma unroll
    for (int c = 0; c < 8; ++c) {
        f32x4 v = *(const f32x4*)(smem + naddr32(R, c));
        #pragma unroll
        for (int e = 0; e < 4; ++e) h[c * 4 + e] = v[e];
    }
    float lg[OUT_N];
    #pragma unroll
    for (int o = 0; o < OUT_N; ++o) {
        const float* w = Wout_w + o * 32;
        float s = 0.f;
        #pragma unroll
        for (int x = 0; x < 32; ++x) s = fmaf(w[x], h[x], s);
        lg[o] = s + Wout_b[o];
    }
    float m = lg[0];
    #pragma unroll
    for (int o = 1; o < OUT_N; ++o) m = fmaxf(m, lg[o]);
    float sum = 0.f;
    #pragma unroll
    for (int o = 0; o < OUT_N; ++o) sum += expf(lg[o] - m);
    float lse = m + logf(sum);
    #pragma unroll
    for (int o = 0; o < OUT_N; ++o) out[g * OUT_N + o] = lg[o] - lse;
}

// ---------------------------------------------------------------------------
// L1 kernel: embed gather (fp32) + exact leaf logits + level 1 + h1 logits.
// Block = 16 L1 nodes, 4 waves = splitK4, both ntiles per wave. 1024 blocks.
// smem: rows 0..31 leaves, 32..47 h1 (fp32, 128B rows) | scratch 3x2KB @6144.
// ---------------------------------------------------------------------------
__global__ __launch_bounds__(256, 4) void l1_kernel(
    const int* __restrict__ word_ids, const float* __restrict__ embed,
    const unsigned short* __restrict__ Bg, const float* __restrict__ bias,
    const float* __restrict__ Wout_w, const float* __restrict__ Wout_b,
    float* __restrict__ h1buf, float* __restrict__ out)
{
    __shared__ char smem[6144 + 6144];
    const int tid = threadIdx.x, lane = tid & 63;
    const int l15 = lane & 15, hi = lane >> 4, u = tid >> 6;
    const int tile = blockIdx.x;

    // ---- stage 32 leaf rows fp32 (rotated chunks) + exact leaf logits -----
    {
        int rr = tid >> 3, q4 = tid & 7;          // 8 threads per leaf row
        int r = rr >> 1, child = rr & 1;
        int g1 = tile * 16 + r;
        int leaf = (g1 >> 5) * 64 + (g1 & 31) * 2 + child;
        int wid = word_ids[leaf];
        f32x4 v = ((const f32x4*)(embed + (size_t)wid * 32))[q4];
        *(f32x4*)(smem + naddr32(rr, q4)) = v;

        float lg[OUT_N];
        #pragma unroll
        for (int o = 0; o < OUT_N; ++o) {
            const float* w = Wout_w + o * 32 + q4 * 4;
            lg[o] = w[0]*v[0] + w[1]*v[1] + w[2]*v[2] + w[3]*v[3];
        }
        #pragma unroll
        for (int o = 0; o < OUT_N; ++o) {
            lg[o] += __shfl_xor(lg[o], 1, 64);
            lg[o] += __shfl_xor(lg[o], 2, 64);
            lg[o] += __shfl_xor(lg[o], 4, 64);
        }
        if (q4 == 0) {
            #pragma unroll
            for (int o = 0; o < OUT_N; ++o) lg[o] += Wout_b[o];
            float m = lg[0];
            #pragma unroll
            for (int o = 1; o < OUT_N; ++o) m = fmaxf(m, lg[o]);
            float sum = 0.f;
            #pragma unroll
            for (int o = 0; o < OUT_N; ++o) sum += expf(lg[o] - m);
            float lse = m + logf(sum);
            #pragma unroll
            for (int o = 0; o < OUT_N; ++o) out[(size_t)leaf * OUT_N + o] = lg[o] - lse;
        }
    }
    __syncthreads();

    float crot[64];
    load_crot32(smem, 2 * l15, hi, crot);

    f32x4 a0 = {0.f,0.f,0.f,0.f}, a1 = {0.f,0.f,0.f,0.f};
    if      (u == 0) run2_k< 0, 17>(Bg, crot, lane, a0, a1);
    else if (u == 1) run2_k<17, 34>(Bg, crot, lane, a0, a1);
    else if (u == 2) run2_k<34, 50>(Bg, crot, lane, a0, a1);
    else             run2_k<50, 67>(Bg, crot, lane, a0, a1);

    if (u > 0) {
        char* sp = smem + 6144 + (u - 1) * 2048 + lane * 32;
        *(f32x4*)sp = a0; *((f32x4*)sp + 1) = a1;
    }
    __syncthreads();
    if (u == 0) {
        #pragma unroll
        for (int v2 = 0; v2 < 3; ++v2) {
            const char* sp = smem + 6144 + v2 * 2048 + lane * 32;
            a0 += *(const f32x4*)sp;
            a1 += *((const f32x4*)sp + 1);
        }
        float bk0 = bias[l15], bk1 = bias[16 + l15];
        #pragma unroll
        for (int r = 0; r < 4; ++r) {
            int row = hi * 4 + r;
            int node = tile * 16 + row;
            float h0 = tanhf(a0[r] + bk0), h1v = tanhf(a1[r] + bk1);
            h1buf[(size_t)node * 32 + l15]      = h0;
            h1buf[(size_t)node * 32 + 16 + l15] = h1v;
            store_h32(smem, 32 + row, l15, h0);
            store_h32(smem, 32 + row, 16 + l15, h1v);
        }
    }
    __syncthreads();
    if (tid < 16)
        node_logits32(smem, 32 + tid, Wout_w, Wout_b, out,
                      (size_t)32768 + tile * 16 + tid);
}

// ---------------------------------------------------------------------------
// Tail deep level (L3..L6): packed 2-tree tile, 8 waves = splitK8, both n.
// ---------------------------------------------------------------------------
constexpr int SCR_T = 16384;

template<int RPT, int CHILDB, int OUTB, bool ROOT>
static __device__ __forceinline__ void level_deep(
    char* smem, const unsigned short* __restrict__ Bg,
    const float* __restrict__ bias, float* __restrict__ roots,
    int bid, int lane, int wave)
{
    const int l15 = lane & 15, hi = lane >> 4;
    int rc = (l15 < 2 * RPT) ? l15 : 0;
    int tree = rc / RPT, i = rc % RPT;
    float crot[64];
    load_crot32(smem, tree * 64 + CHILDB + 2 * i, hi, crot);

    f32x4 a0 = {0.f,0.f,0.f,0.f}, a1 = {0.f,0.f,0.f,0.f};
    switch (wave) {
        case 0:  run2_k< 0,  9>(Bg, crot, lane, a0, a1); break;
        case 1:  run2_k< 9, 17>(Bg, crot, lane, a0, a1); break;
        case 2:  run2_k<17, 26>(Bg, crot, lane, a0, a1); break;
        case 3:  run2_k<26, 34>(Bg, crot, lane, a0, a1); break;
        case 4:  run2_k<34, 42>(Bg, crot, lane, a0, a1); break;
        case 5:  run2_k<42, 50>(Bg, crot, lane, a0, a1); break;
        case 6:  run2_k<50, 59>(Bg, crot, lane, a0, a1); break;
        default: run2_k<59, 67>(Bg, crot, lane, a0, a1); break;
    }
    if (wave > 0) {
        char* sp = smem + SCR_T + (wave - 1) * 2048 + lane * 32;
        *(f32x4*)sp = a0; *((f32x4*)sp + 1) = a1;
    }
    __syncthreads();
    if (wave == 0) {
        #pragma unroll
        for (int v2 = 0; v2 < 7; ++v2) {
            const char* sp = smem + SCR_T + v2 * 2048 + lane * 32;
            a0 += *(const f32x4*)sp;
            a1 += *((const f32x4*)sp + 1);
        }
        float bk0 = bias[l15], bk1 = bias[16 + l15];
        #pragma unroll
        for (int r4 = 0; r4 < 4; ++r4) {
            int row = hi * 4 + r4;
            if (row < 2 * RPT) {
                float h0 = tanhf(a0[r4] + bk0), h1v = tanhf(a1[r4] + bk1);
                int t2 = row / RPT, i2 = row % RPT;
                int R2 = t2 * 64 + OUTB + i2;
                store_h32(smem, R2, l15, h0);
                store_h32(smem, R2, 16 + l15, h1v);
                if (ROOT) {
                    roots[(size_t)(bid * 2 + t2) * 32 + l15]      = h0;
                    roots[(size_t)(bid * 2 + t2) * 32 + 16 + l15] = h1v;
                }
            }
        }
    }
    __syncthreads();
}

// ---------------------------------------------------------------------------
// Tail kernel: levels 2..6 + logits for L2..L6 nodes. Block = 2 trees.
// fp32 LDS rows per tree (stride 64): h1 0..31, L2 32..47, L3 48..55,
// L4 56..59, L5 60..61, L6 62.  Scratch: 7 x 2KB @16384.
// ---------------------------------------------------------------------------
__global__ __launch_bounds__(512, 2) void tail_kernel(
    const unsigned short* __restrict__ Bg, const float* __restrict__ bias,
    const float* __restrict__ h1buf,
    const float* __restrict__ Wout_w, const float* __restrict__ Wout_b,
    float* __restrict__ out)
{
    __shared__ char smem[16384 + 14336];
    const int tid = threadIdx.x, lane = tid & 63;
    const int l15 = lane & 15, hi = lane >> 4, wave = tid >> 6;
    const int bid = blockIdx.x;
    float* roots = out + ROOTS_OFF;

    // stage 2 trees' h1 fp32 (8 KB): 512 threads x 16 B
    {
        int gRow = tid >> 3, c4 = tid & 7;       // 64 rows x 8 chunks
        int t = gRow >> 5, i = gRow & 31;
        f32x4 v = *(const f32x4*)(h1buf + ((size_t)(bid * 2 + t) * 32 + i) * 32 + c4 * 4);
        *(f32x4*)(smem + naddr32(t * 64 + i, c4)) = v;
    }
    __syncthreads();

    // ---- L2: tree2 x splitK4, both ntiles ---------------------------------
    {
        const int t = wave >> 2, u = wave & 3;
        float crot[64];
        load_crot32(smem, t * 64 + 2 * l15, hi, crot);
        f32x4 a0 = {0.f,0.f,0.f,0.f}, a1 = {0.f,0.f,0.f,0.f};
        if      (u == 0) run2_k< 0, 17>(Bg, crot, lane, a0, a1);
        else if (u == 1) run2_k<17, 34>(Bg, crot, lane, a0, a1);
        else if (u == 2) run2_k<34, 50>(Bg, crot, lane, a0, a1);
        else             run2_k<50, 67>(Bg, crot, lane, a0, a1);
        if (u > 0) {
            char* sp = smem + SCR_T + (t * 3 + u - 1) * 2048 + lane * 32;
            *(f32x4*)sp = a0; *((f32x4*)sp + 1) = a1;
        }
        __syncthreads();
        if (u == 0) {
            #pragma unroll
            for (int v2 = 0; v2 < 3; ++v2) {
                const char* sp = smem + SCR_T + (t * 3 + v2) * 2048 + lane * 32;
                a0 += *(const f32x4*)sp;
                a1 += *((const f32x4*)sp + 1);
            }
            float bk0 = bias[l15], bk1 = bias[16 + l15];
            #pragma unroll
            for (int r4 = 0; r4 < 4; ++r4) {
                int row = hi * 4 + r4;
                int R2 = t * 64 + 32 + row;
                float h0 = tanhf(a0[r4] + bk0), h1v = tanhf(a1[r4] + bk1);
                store_h32(smem, R2, l15, h0);
                store_h32(smem, R2, 16 + l15, h1v);
            }
        }
        __syncthreads();
    }

    // ---- L3..L6 -----------------------------------------------------------
    level_deep<8, 32, 48, false>(smem, Bg, bias, roots, bid, lane, wave);
    level_deep<4, 48, 56, false>(smem, Bg, bias, roots, bid, lane, wave);
    level_deep<2, 56, 60, false>(smem, Bg, bias, roots, bid, lane, wave);
    level_deep<1, 60, 62, true >(smem, Bg, bias, roots, bid, lane, wave);

    // ---- logits for the block's 62 internal nodes (L2..L6) ----------------
    if (tid < 62) {
        int t = (tid >= 31) ? 1 : 0;
        int rr = tid - 31 * t;
        int R; size_t g;
        int tg = bid * 2 + t;
        if (rr < 16)      { R = t*64 + 32 + rr;        g = 49152 + (size_t)tg*16 + rr; }
        else if (rr < 24) { R = t*64 + 48 + (rr-16);   g = 57344 + (size_t)tg*8  + (rr-16); }
        else if (rr < 28) { R = t*64 + 56 + (rr-24);   g = 61440 + (size_t)tg*4  + (rr-24); }
        else if (rr < 30) { R = t*64 + 60 + (rr-28);   g = 63488 + (size_t)tg*2  + (rr-28); }
        else              { R = t*64 + 62;             g = 64512 + (size_t)tg; }
        node_logits32(smem, R, Wout_w, Wout_b, out, g);
    }
}

// ---------------------------------------------------------------------------
extern "C" void kernel_launch(void* const* d_in, const int* in_sizes, int n_in,
                              void* d_out, int out_size, void* d_ws, size_t ws_size,
                              hipStream_t stream)
{
    const int*   word_ids = (const int*)  d_in[0];
    const float* embed    = (const float*)d_in[1];
    const float* V        = (const float*)d_in[2];
    const float* W        = (const float*)d_in[3];
    const float* bvec     = (const float*)d_in[4];
    const float* Wout_w   = (const float*)d_in[5];
    const float* Wout_b   = (const float*)d_in[6];
    float* out = (float*)d_out;

    // ws: Bfrag [137216 B] | h1buf 16384 nodes x 32 fp32 [2,097,152 B]
    unsigned short* Bfrag = (unsigned short*)d_ws;
    float* h1buf = (float*)((char*)d_ws + 137216);

    bprep_kernel<<<134, 64, 0, stream>>>(V, W, Bfrag);
    l1_kernel<<<1024, 256, 0, stream>>>(word_ids, embed, Bfrag, bvec,
                                        Wout_w, Wout_b, h1buf, out);
    tail_kernel<<<256, 512, 0, stream>>>(Bfrag, bvec, h1buf, Wout_w, Wout_b, out);
}